// Round 15
// baseline (28281.793 us; speedup 1.0000x reference)
//
#include <hip/hip_runtime.h>

typedef unsigned u2v __attribute__((ext_vector_type(2)));

#define NS 99985

// ---- XOR-butterfly reduction, all-VALU builtins (proven) ----------------
template<int CTRL>
__device__ __forceinline__ float dpp_xadd(float v) {
    int s = __builtin_amdgcn_update_dpp(0, __float_as_int(v), CTRL, 0xF, 0xF, true);
    return v + __int_as_float(s);
}
#if __has_builtin(__builtin_amdgcn_permlane16_swap)
__device__ __forceinline__ float xor16_add(float v) {
    u2v r = __builtin_amdgcn_permlane16_swap((unsigned)__float_as_int(v),
                                             (unsigned)__float_as_int(v),
                                             false, false);
    return __int_as_float((int)r.x) + __int_as_float((int)r.y);
}
#else
__device__ __forceinline__ float xor16_add(float v) {
    int s = __builtin_amdgcn_ds_swizzle(__float_as_int(v), 0x401F);
    return v + __int_as_float(s);
}
#endif
__device__ __forceinline__ float red32(float v) {
    v = dpp_xadd<0xB1>(v); v = dpp_xadd<0x4E>(v);
    v = dpp_xadd<0x141>(v); v = dpp_xadd<0x140>(v);
    return xor16_add(v);
}

// ---- precompute: tab8[2n]=(s,C1r,C1i,0)  tab8[2n+1]=(C2r,C2i,C3r,C3i) ---
// Ck_n = sum conj(u_{n-k})*u_n ; s_n = LRW/(sum|u_n|^2+eps)
__global__ void pre_tab8(const float* __restrict__ xre,
                         const float* __restrict__ xim,
                         float4* __restrict__ tab8, int ns) {
    int n = blockIdx.x * blockDim.x + threadIdx.x;
    if (n >= ns) return;
    const float* ar = xre + 4 * n;
    const float* ai = xim + 4 * n;
    float un = 0.f;
    #pragma unroll 8
    for (int k = 0; k < 64; ++k) un = fmaf(ar[k], ar[k], fmaf(ai[k], ai[k], un));
    float s = (1.0f / 64.0f) / (un + 1e-8f);
    float C[3][2];
    #pragma unroll
    for (int j = 1; j <= 3; ++j) {
        float cr = 0.f, ci = 0.f;
        if (n >= j) {
            const float* pr = ar - 4 * j;
            const float* pi = ai - 4 * j;
            #pragma unroll 8
            for (int k = 0; k < 64; ++k) {
                cr = fmaf(pr[k], ar[k], fmaf(pi[k], ai[k], cr));
                ci = fmaf(pr[k], ai[k], ci);
                ci = fmaf(-pi[k], ar[k], ci);
            }
        }
        C[j - 1][0] = cr; C[j - 1][1] = ci;
    }
    tab8[2 * n]     = make_float4(s, C[0][0], C[0][1], 0.f);
    tab8[2 * n + 1] = make_float4(C[1][0], C[1][1], C[2][0], C[2][1]);
}

// ---- 2-wave scan, 2 steps per barrier (stale-by-3 base) -----------------
// LDS: sh[4Q+2j+h] = B (base) slots; sh[8+4Q+2j+h] = ews slots.
__global__ __launch_bounds__(128, 1)
void ddlms_scan3(const float* __restrict__ xre,
                 const float* __restrict__ xim,
                 const float4* __restrict__ tab8,
                 float* __restrict__ out) {
    const int tid = (int)threadIdx.x;
    const int wid = tid >> 6;
    const int l = tid & 63;
    const int m = l & 31;
    const int half = l >> 5;

    constexpr float EPSv = 1e-8f;
    constexpr float LRF  = 1.0f / 128.0f;
    constexpr float LRB  = 1.0f / 2048.0f;
    const float B1 = 0.6324555320336759f;
    const float A1 = 0.31622776601683794f;
    const float A3 = 0.9486832980505138f;

    __shared__ float2 sh[16];
    if (tid < 16) sh[tid] = make_float2(0.f, 0.f);
    __syncthreads();

    float2* __restrict__ o2 = reinterpret_cast<float2*>(out);

    if (wid == 0) {
        // -------- consumer: scalar chain; holds ews_{n-1,n-2,n-3} --------
        float fr = 1.f, fi = 0.f, br = 0.f, bi = 0.f, psr = 1.f, psj = 0.f;
        float e1r = 0.f, e1i = 0.f, e2r = 0.f, e2i = 0.f, e3r = 0.f, e3i = 0.f;

        auto CSTEP = [&](int n, int Q, int j, const float4& tA, const float4& tB,
                         bool tail) {
            float2 B = sh[4 * Q + 2 * j + half];
            float vr = B.x, vi = B.y;
            vr = fmaf(e1r, tA.y, vr); vr = fmaf(-e1i, tA.z, vr);
            vi = fmaf(e1r, tA.z, vi); vi = fmaf( e1i, tA.y, vi);
            vr = fmaf(e2r, tB.x, vr); vr = fmaf(-e2i, tB.y, vr);
            vi = fmaf(e2r, tB.y, vi); vi = fmaf( e2i, tB.x, vi);
            vr = fmaf(e3r, tB.z, vr); vr = fmaf(-e3i, tB.w, vr);
            vi = fmaf(e3r, tB.w, vi); vi = fmaf( e3i, tB.z, vi);

            float kr = fmaf(vr, fr, -(vi * fi));
            float ki = fmaf(vr, fi,   vi * fr);
            float zr = kr + br, zi = ki + bi;
            if (m == 0) o2[2 * n + half] = make_float2(zr, zi);

            float magr = (fabsf(zr) > B1) ? A3 : A1;
            float dr   = (zr <= 0.f) ? -magr : magr;
            float magi = (fabsf(zi) > B1) ? A3 : A1;
            float di   = (zi <= 0.f) ? -magi : magi;

            float er = dr - zr, ei = di - zi;

            float v2  = fmaf(vr, vr, fmaf(vi, vi, EPSv));
            float rv  = __builtin_amdgcn_rcpf(v2);
            float gfr = fmaf(er, vr,   ei * vi)  * rv;
            float gfi = fmaf(ei, vr, -(er * vi)) * rv;
            float m2  = fmaf(gfr, gfr, gfi * gfi);
            float scf = fminf(1.f, 30.f * __builtin_amdgcn_rsqf(m2));
            float tf  = LRF * scf;

            float dbr = dr - br, dbi = di - bi;
            float ewr = fmaf(dbr, psr, -(dbi * psj)) - vr;
            float ewi = fmaf(dbr, psj,   dbi * psr)  - vi;

            if (!tail) {
                float ewsr = tA.x * ewr, ewsi = tA.x * ewi;   // s_n * ew_n
                if (m == 0) sh[8 + 4 * Q + 2 * j + half] = make_float2(ewsr, ewsi);
                e3r = e2r; e3i = e2i; e2r = e1r; e2i = e1i; e1r = ewsr; e1i = ewsi;
            }

            fr = fmaf(tf, gfr, fr); fi = fmaf(tf, gfi, fi);
            br = fmaf(LRB, er, br); bi = fmaf(LRB, ei, bi);
            float ff = fmaf(fr, fr, fi * fi);
            float rs = __builtin_amdgcn_rsqf(ff);
            psr = fr * rs; psj = -(fi * rs);
        };

        auto PREF = [&](int n0, float4& a0, float4& b0, float4& a1, float4& b1) {
            int na = n0;     if (na > NS - 1) na = NS - 1;
            int nb = n0 + 1; if (nb > NS - 1) nb = NS - 1;
            a0 = tab8[2 * na]; b0 = tab8[2 * na + 1];
            a1 = tab8[2 * nb]; b1 = tab8[2 * nb + 1];
        };

        float4 cA0 = tab8[0], cB0 = tab8[1], cA1 = tab8[2], cB1 = tab8[3];
        float4 nA0, nB0, nA1, nB1;

        int n = 0;
        for (int it = 0; it < 24996; ++it) {      // 4 steps (2 phases) / iter
            CSTEP(n,     0, 0, cA0, cB0, false);
            CSTEP(n + 1, 0, 1, cA1, cB1, false);
            PREF(n + 2, nA0, nB0, nA1, nB1);
            __syncthreads();
            CSTEP(n + 2, 1, 0, nA0, nB0, false);
            CSTEP(n + 3, 1, 1, nA1, nB1, false);
            PREF(n + 4, cA0, cB0, cA1, cB1);
            __syncthreads();
            n += 4;
        }
        CSTEP(99984, 0, 0, cA0, cB0, true);       // tail step
    } else {
        // -------- producer: w + stale bases, 3 rotating u-pairs ----------
        float wAr = 0.f, wAi = 0.f, wBr = 0.f, wBi = 0.f;

        auto LOADU = [&](int nn, float& a, float& b_, float& c, float& d_) {
            if (nn > NS - 1) nn = NS - 1;
            const float* pr = xre + 4 * nn;
            const float* pi = xim + 4 * nn;
            a = pr[m]; c = pr[m + 32]; b_ = pi[m]; d_ = pi[m + 32];
        };

        // pair[p] holds u for 2 consecutive steps: {0:first, 1:second}
        float p0[8], p1[8], p2[8];
        #pragma unroll
        for (int q = 0; q < 8; ++q) p0[q] = 0.f;        // u_{-2}, u_{-1}
        LOADU(0, p1[0], p1[1], p1[2], p1[3]);
        LOADU(1, p1[4], p1[5], p1[6], p1[7]);
        LOADU(2, p2[0], p2[1], p2[2], p2[3]);
        LOADU(3, p2[4], p2[5], p2[6], p2[7]);

        auto PSTEP = [&](int n2k, int Q, float* W, float* Bp) {
            float2 ea = sh[8 + 4 * (1 - Q) + 0 + half];   // ews_{2k-2}
            float2 eb = sh[8 + 4 * (1 - Q) + 2 + half];   // ews_{2k-1}
            // w_{2k-1} = w_{2k-2} + ea (x) conj(u_{2k-2})
            wAr = fmaf(ea.x, W[0], fmaf( ea.y, W[1], wAr));
            wAi = fmaf(ea.y, W[0], fmaf(-ea.x, W[1], wAi));
            wBr = fmaf(ea.x, W[2], fmaf( ea.y, W[3], wBr));
            wBi = fmaf(ea.y, W[2], fmaf(-ea.x, W[3], wBi));
            // B_{2k+2} = red(w_{2k-1} * u_{2k+2})
            {
                float prr = wAr * Bp[0]; prr = fmaf(-wAi, Bp[1], prr);
                prr = fmaf(wBr, Bp[2], prr); prr = fmaf(-wBi, Bp[3], prr);
                float pri = wAr * Bp[1]; pri = fmaf( wAi, Bp[0], pri);
                pri = fmaf(wBr, Bp[3], pri); pri = fmaf( wBi, Bp[2], pri);
                float basr = red32(prr), basi = red32(pri);
                if (m == 0) sh[4 * (1 - Q) + 0 + half] = make_float2(basr, basi);
            }
            // w_{2k} = w_{2k-1} + eb (x) conj(u_{2k-1})
            wAr = fmaf(eb.x, W[4], fmaf( eb.y, W[5], wAr));
            wAi = fmaf(eb.y, W[4], fmaf(-eb.x, W[5], wAi));
            wBr = fmaf(eb.x, W[6], fmaf( eb.y, W[7], wBr));
            wBi = fmaf(eb.y, W[6], fmaf(-eb.x, W[7], wBi));
            // B_{2k+3} = red(w_{2k} * u_{2k+3})
            {
                float prr = wAr * Bp[4]; prr = fmaf(-wAi, Bp[5], prr);
                prr = fmaf(wBr, Bp[6], prr); prr = fmaf(-wBi, Bp[7], prr);
                float pri = wAr * Bp[5]; pri = fmaf( wAi, Bp[4], pri);
                pri = fmaf(wBr, Bp[7], pri); pri = fmaf( wBi, Bp[6], pri);
                float basr = red32(prr), basi = red32(pri);
                if (m == 0) sh[4 * (1 - Q) + 2 + half] = make_float2(basr, basi);
            }
            // prefetch u_{2k+4}, u_{2k+5} into the just-freed W pair
            LOADU(n2k + 4, W[0], W[1], W[2], W[3]);
            LOADU(n2k + 5, W[4], W[5], W[6], W[7]);
        };

        int n0 = 0;
        for (int i = 0; i < 8332; ++i) {          // 6 phases (12 steps) / iter
            PSTEP(n0,      0, p0, p2); __syncthreads();
            PSTEP(n0 + 2,  1, p1, p0); __syncthreads();
            PSTEP(n0 + 4,  0, p2, p1); __syncthreads();
            PSTEP(n0 + 6,  1, p0, p2); __syncthreads();
            PSTEP(n0 + 8,  0, p1, p0); __syncthreads();
            PSTEP(n0 + 10, 1, p2, p1); __syncthreads();
            n0 += 12;
        }
    }
}

// ---- fallback: single-wave, no workspace (R10-class) --------------------
__global__ __launch_bounds__(64, 1)
void ddlms_scan_fb(const float* __restrict__ xre,
                   const float* __restrict__ xim,
                   float* __restrict__ out) {
    const int l = (int)threadIdx.x;
    const int m = l & 31;
    const int half = l >> 5;
    constexpr float EPSv = 1e-8f;
    constexpr float LRW  = 1.0f / 64.0f;
    constexpr float LRF  = 1.0f / 128.0f;
    constexpr float LRB  = 1.0f / 2048.0f;
    const float B1 = 0.6324555320336759f;
    const float A1 = 0.31622776601683794f;
    const float A3 = 0.9486832980505138f;
    float wAr=0.f, wAi=0.f, wBr=0.f, wBi=0.f;
    float fr=1.f, fi=0.f, br=0.f, bi=0.f, psr=1.f, psj=0.f;
    float vr=0.f, vi=0.f, ewPr=0.f, ewPi=0.f, sP=0.f;
    float2* __restrict__ o2 = reinterpret_cast<float2*>(out);
    auto LOADU = [&](int nn, float& a, float& b_, float& c, float& d_) {
        const float* pr = xre + 4 * nn;
        const float* pi = xim + 4 * nn;
        a = pr[m]; c = pr[m + 32]; b_ = pi[m]; d_ = pi[m + 32];
    };
    float pAr,pAi,pBr,pBi, qAr,qAi,qBr,qBi, rAr,rAi,rBr,rBi;
    pAr=pAi=pBr=pBi=0.f;
    LOADU(0, qAr,qAi,qBr,qBi);
    LOADU(1, rAr,rAi,rBr,rBi);
    auto STEP = [&](int n,
        float& uPAr, float& uPAi, float& uPBr, float& uPBi,
        float& uCAr, float& uCAi, float& uCBr, float& uCBi,
        float& uNAr, float& uNAi, float& uNBr, float& uNBi) {
        {
            float gr = ewPr * uPAr; gr = fmaf( ewPi, uPAi, gr);
            float gi = ewPi * uPAr; gi = fmaf(-ewPr, uPAi, gi);
            wAr = fmaf(sP, gr, wAr); wAi = fmaf(sP, gi, wAi);
            float hr = ewPr * uPBr; hr = fmaf( ewPi, uPBi, hr);
            float hi = ewPi * uPBr; hi = fmaf(-ewPr, uPBi, hi);
            wBr = fmaf(sP, hr, wBr); wBi = fmaf(sP, hi, wBi);
        }
        float basr, basi;
        {
            float prr = wAr * uNAr; prr = fmaf(-wAi, uNAi, prr);
            prr = fmaf(wBr, uNBr, prr); prr = fmaf(-wBi, uNBi, prr);
            float pri = wAr * uNAi; pri = fmaf( wAi, uNAr, pri);
            pri = fmaf(wBr, uNBi, pri); pri = fmaf( wBi, uNBr, pri);
            basr = red32(prr); basi = red32(pri);
        }
        float uu = uCAr*uCAr; uu = fmaf(uCAi,uCAi,uu);
        uu = fmaf(uCBr,uCBr,uu); uu = fmaf(uCBi,uCBi,uu);
        float sN = LRW * __builtin_amdgcn_rcpf(red32(uu) + EPSv);
        float ccr = uCAr*uNAr; ccr = fmaf(uCAi,uNAi,ccr);
        ccr = fmaf(uCBr,uNBr,ccr); ccr = fmaf(uCBi,uNBi,ccr);
        float cci = uCAr*uNAi; cci = fmaf(-uCAi,uNAr,cci);
        cci = fmaf(uCBr,uNBi,cci); cci = fmaf(-uCBi,uNBr,cci);
        float sCr = sN * red32(ccr), sCi = sN * red32(cci);
        float kr = fmaf(vr, fr, -(vi * fi));
        float ki = fmaf(vr, fi,   vi * fr);
        float zr = kr + br, zi = ki + bi;
        if (m == 0) o2[2 * n + half] = make_float2(zr, zi);
        float magr = (fabsf(zr) > B1) ? A3 : A1;
        float dr   = (zr <= 0.f) ? -magr : magr;
        float magi = (fabsf(zi) > B1) ? A3 : A1;
        float di   = (zi <= 0.f) ? -magi : magi;
        float er = dr - zr, ei = di - zi;
        float v2  = fmaf(vr, vr, fmaf(vi, vi, EPSv));
        float rv  = __builtin_amdgcn_rcpf(v2);
        float gfr = fmaf(er, vr,   ei * vi)  * rv;
        float gfi = fmaf(ei, vr, -(er * vi)) * rv;
        float m2  = fmaf(gfr, gfr, gfi * gfi);
        float scf = fminf(1.f, 30.f * __builtin_amdgcn_rsqf(m2));
        float tf  = LRF * scf;
        float dbr = dr - br, dbi = di - bi;
        float ewr = fmaf(dbr, psr, -(dbi * psj)) - vr;
        float ewi = fmaf(dbr, psj,   dbi * psr)  - vi;
        float Dr = fmaf(ewr, sCr, -(ewi * sCi));
        float Di = fmaf(ewr, sCi,   ewi * sCr);
        vr = basr + Dr; vi = basi + Di;
        fr = fmaf(tf, gfr, fr); fi = fmaf(tf, gfi, fi);
        br = fmaf(LRB, er, br); bi = fmaf(LRB, ei, bi);
        float ff = fmaf(fr, fr, fi * fi);
        float rs = __builtin_amdgcn_rsqf(ff);
        psr = fr * rs; psj = -(fi * rs);
        ewPr = ewr; ewPi = ewi; sP = sN;
        int nn = n + 2; if (nn > NS - 1) nn = NS - 1;
        LOADU(nn, uPAr, uPAi, uPBr, uPBi);
    };
    int n = 0;
    for (int it = 0; it < 33328; ++it) {
        STEP(n,     pAr,pAi,pBr,pBi,  qAr,qAi,qBr,qBi,  rAr,rAi,rBr,rBi);
        STEP(n + 1, qAr,qAi,qBr,qBi,  rAr,rAi,rBr,rBi,  pAr,pAi,pBr,pBi);
        STEP(n + 2, rAr,rAi,rBr,rBi,  pAr,pAi,pBr,pBi,  qAr,qAi,qBr,qBi);
        n += 3;
    }
    STEP(99984, pAr,pAi,pBr,pBi, qAr,qAi,qBr,qBi, rAr,rAi,rBr,rBi);
}

extern "C" void kernel_launch(void* const* d_in, const int* in_sizes, int n_in,
                              void* d_out, int out_size, void* d_ws, size_t ws_size,
                              hipStream_t stream) {
    const float* xre = (const float*)d_in[0];
    const float* xim = (const float*)d_in[1];
    float* out = (float*)d_out;

    if (ws_size >= (size_t)2 * NS * sizeof(float4)) {
        float4* tab8 = (float4*)d_ws;
        pre_tab8<<<(NS + 255) / 256, 256, 0, stream>>>(xre, xim, tab8, NS);
        ddlms_scan3<<<1, 128, 0, stream>>>(xre, xim, tab8, out);
    } else {
        ddlms_scan_fb<<<1, 64, 0, stream>>>(xre, xim, out);
    }
}

// Round 17
// 19843.782 us; speedup vs baseline: 1.4252x; 1.4252x over previous
//
#include <hip/hip_runtime.h>

typedef unsigned u2v __attribute__((ext_vector_type(2)));

#define NSTEPS 99985

// ---- XOR-butterfly reduction, all-VALU builtins (proven) ----------------
template<int CTRL>
__device__ __forceinline__ float dpp_xadd(float v) {
    int s = __builtin_amdgcn_update_dpp(0, __float_as_int(v), CTRL, 0xF, 0xF, true);
    return v + __int_as_float(s);
}
#if __has_builtin(__builtin_amdgcn_permlane16_swap)
__device__ __forceinline__ float xor16_add(float v) {
    u2v r = __builtin_amdgcn_permlane16_swap((unsigned)__float_as_int(v),
                                             (unsigned)__float_as_int(v),
                                             false, false);
    return __int_as_float((int)r.x) + __int_as_float((int)r.y);
}
#else
__device__ __forceinline__ float xor16_add(float v) {
    int s = __builtin_amdgcn_ds_swizzle(__float_as_int(v), 0x401F);
    return v + __int_as_float(s);
}
#endif
__device__ __forceinline__ float red32(float v) {
    v = dpp_xadd<0xB1>(v); v = dpp_xadd<0x4E>(v);
    v = dpp_xadd<0x141>(v); v = dpp_xadd<0x140>(v);
    return xor16_add(v);
}

// ---- relaxed barrier: order LDS only; do NOT drain vmcnt ----------------
// __syncthreads() emits s_waitcnt vmcnt(0) lgkmcnt(0) + s_barrier, draining
// our global prefetches every step (~200 cy exposed). Only the LDS handshake
// (sh[] writes/reads) crosses waves -> lgkmcnt(0) suffices. Compiler still
// inserts vmcnt(N) before each USE of prefetched registers.
__device__ __forceinline__ void wave_barrier() {
    asm volatile("s_waitcnt lgkmcnt(0)" ::: "memory");
    __builtin_amdgcn_s_barrier();
    asm volatile("" ::: "memory");      // no LDS reads hoisted above barrier
}

// ---- parallel precompute: tab[n] = (s, s*Cr, s*Ci, 0) -------------------
__global__ void pre_tab(const float* __restrict__ xre,
                        const float* __restrict__ xim,
                        float4* __restrict__ tab, int ns) {
    int n = blockIdx.x * blockDim.x + threadIdx.x;
    if (n >= ns) return;
    const float* ar = xre + 4 * n;
    const float* ai = xim + 4 * n;
    float un = 0.f;
    #pragma unroll 8
    for (int k = 0; k < 64; ++k) un = fmaf(ar[k], ar[k], fmaf(ai[k], ai[k], un));
    float s = (1.0f / 64.0f) / (un + 1e-8f);
    float cr = 0.f, ci = 0.f;
    if (n + 1 < ns) {
        const float* br_ = ar + 4;
        const float* bi_ = ai + 4;
        #pragma unroll 8
        for (int k = 0; k < 64; ++k) {
            cr = fmaf(ar[k], br_[k], fmaf(ai[k], bi_[k], cr));
            ci = fmaf(ar[k], bi_[k], ci);
            ci = fmaf(-ai[k], br_[k], ci);
        }
    }
    tab[n] = make_float4(s, s * cr, s * ci, 0.f);
}

// ---- 2-wave producer/consumer scan (R14 structure, relaxed barriers) ----
__global__ __launch_bounds__(128, 1)
void ddlms_scan2(const float* __restrict__ xre,
                 const float* __restrict__ xim,
                 const float4* __restrict__ tab,
                 float* __restrict__ out) {
    const int tid = (int)threadIdx.x;
    const int wid = tid >> 6;
    const int l = tid & 63;
    const int m = l & 31;
    const int half = l >> 5;

    constexpr float EPSv = 1e-8f;
    constexpr float LRF  = 1.0f / 128.0f;
    constexpr float LRB  = 1.0f / 2048.0f;
    const float B1 = 0.6324555320336759f;
    const float A1 = 0.31622776601683794f;
    const float A3 = 0.9486832980505138f;

    __shared__ float2 sh[8];
    if (tid < 8) sh[tid] = make_float2(0.f, 0.f);
    __syncthreads();

    float2* __restrict__ o2 = reinterpret_cast<float2*>(out);

    if (wid == 0) {
        // ---------------- consumer: scalar chain ----------------
        float fr = 1.f, fi = 0.f, br = 0.f, bi = 0.f, psr = 1.f, psj = 0.f;
        float ewPr = 0.f, ewPi = 0.f, sCPr = 0.f, sCPi = 0.f;
        float4 t0 = tab[0], t1 = tab[1], t2 = tab[2], t3;

        auto W0 = [&](int n, int P, float4& tC, float4& tF) {
            wave_barrier();
            float2 bas = sh[2 * P + half];                 // bas_n (broadcast)
            float Dr = fmaf(ewPr, sCPr, -(ewPi * sCPi));   // D_{n-1}
            float Di = fmaf(ewPr, sCPi,   ewPi * sCPr);
            float vr = bas.x + Dr, vi = bas.y + Di;        // v_n
            { int nn = n + 3; if (nn > NSTEPS - 1) nn = NSTEPS - 1; tF = tab[nn]; }

            float kr = fmaf(vr, fr, -(vi * fi));
            float ki = fmaf(vr, fi,   vi * fr);
            float zr = kr + br, zi = ki + bi;
            if (m == 0) o2[2 * n + half] = make_float2(zr, zi);

            float magr = (fabsf(zr) > B1) ? A3 : A1;
            float dr   = (zr <= 0.f) ? -magr : magr;
            float magi = (fabsf(zi) > B1) ? A3 : A1;
            float di   = (zi <= 0.f) ? -magi : magi;

            float er = dr - zr, ei = di - zi;

            float v2  = fmaf(vr, vr, fmaf(vi, vi, EPSv));
            float rv  = __builtin_amdgcn_rcpf(v2);
            float gfr = fmaf(er, vr,   ei * vi)  * rv;
            float gfi = fmaf(ei, vr, -(er * vi)) * rv;
            float m2  = fmaf(gfr, gfr, gfi * gfi);
            float scf = fminf(1.f, 30.f * __builtin_amdgcn_rsqf(m2));
            float tf  = LRF * scf;

            float dbr = dr - br, dbi = di - bi;
            float ewr = fmaf(dbr, psr, -(dbi * psj)) - vr;
            float ewi = fmaf(dbr, psj,   dbi * psr)  - vi;

            float ewsr = tC.x * ewr, ewsi = tC.x * ewi;    // s_n * ew_n
            if (m == 0) sh[4 + 2 * P + half] = make_float2(ewsr, ewsi);

            fr = fmaf(tf, gfr, fr); fi = fmaf(tf, gfi, fi);
            br = fmaf(LRB, er, br); bi = fmaf(LRB, ei, bi);

            float ff = fmaf(fr, fr, fi * fi);
            float rs = __builtin_amdgcn_rsqf(ff);
            psr = fr * rs; psj = -(fi * rs);

            ewPr = ewr; ewPi = ewi; sCPr = tC.y; sCPi = tC.z;
        };

        int n = 0;
        for (int it = 0; it < 24996; ++it) {   // 4*24996 = 99984
            W0(n + 0, 0, t0, t3);
            W0(n + 1, 1, t1, t0);
            W0(n + 2, 0, t2, t1);
            W0(n + 3, 1, t3, t2);
            n += 4;
        }
        W0(99984, 0, t0, t3);                  // tail (99984 % 4 == 0)
    } else {
        // ---------------- producer: w + base ----------------
        float wAr = 0.f, wAi = 0.f, wBr = 0.f, wBi = 0.f;

        auto LOADU = [&](int nn, float& a, float& b_, float& c, float& d_) {
            const float* pr = xre + 4 * nn;
            const float* pi = xim + 4 * nn;
            a = pr[m]; c = pr[m + 32]; b_ = pi[m]; d_ = pi[m + 32];
        };

        float u0Ar, u0Ai, u0Br, u0Bi, u1Ar, u1Ai, u1Br, u1Bi,
              u2Ar, u2Ai, u2Br, u2Bi, u3Ar, u3Ai, u3Br, u3Bi;
        u3Ar = u3Ai = u3Br = u3Bi = 0.f;       // u_{-1} (ews_{-1} = 0)
        LOADU(0, u0Ar, u0Ai, u0Br, u0Bi);
        LOADU(1, u1Ar, u1Ai, u1Br, u1Bi);
        LOADU(2, u2Ar, u2Ai, u2Br, u2Bi);

        auto W1 = [&](int n, int P,
            float& uPAr, float& uPAi, float& uPBr, float& uPBi,
            float& uNAr, float& uNAi, float& uNBr, float& uNBi) {
            wave_barrier();
            float2 ews = sh[4 + 2 * (1 - P) + half];       // ews_{n-1}
            // w += ews (x) conj(uP)
            wAr = fmaf(ews.x, uPAr, fmaf( ews.y, uPAi, wAr));
            wAi = fmaf(ews.y, uPAr, fmaf(-ews.x, uPAi, wAi));
            wBr = fmaf(ews.x, uPBr, fmaf( ews.y, uPBi, wBr));
            wBi = fmaf(ews.y, uPBr, fmaf(-ews.x, uPBi, wBi));
            // distance-3 prefetch into the now-dead uP slot
            { int nn = n + 3; if (nn > NSTEPS - 1) nn = NSTEPS - 1;
              LOADU(nn, uPAr, uPAi, uPBr, uPBi); }
            // bas_{n+1} = red(w_n * u_{n+1})
            float prr = wAr * uNAr; prr = fmaf(-wAi, uNAi, prr);
            prr = fmaf(wBr, uNBr, prr); prr = fmaf(-wBi, uNBi, prr);
            float pri = wAr * uNAi; pri = fmaf( wAi, uNAr, pri);
            pri = fmaf(wBr, uNBi, pri); pri = fmaf( wBi, uNBr, pri);
            float basr = red32(prr), basi = red32(pri);
            if (m == 0) sh[2 * (1 - P) + half] = make_float2(basr, basi);
        };

        int n = 0;
        for (int it = 0; it < 24996; ++it) {
            W1(n + 0, 0, u3Ar,u3Ai,u3Br,u3Bi, u1Ar,u1Ai,u1Br,u1Bi);
            W1(n + 1, 1, u0Ar,u0Ai,u0Br,u0Bi, u2Ar,u2Ai,u2Br,u2Bi);
            W1(n + 2, 0, u1Ar,u1Ai,u1Br,u1Bi, u3Ar,u3Ai,u3Br,u3Bi);
            W1(n + 3, 1, u2Ar,u2Ai,u2Br,u2Bi, u0Ar,u0Ai,u0Br,u0Bi);
            n += 4;
        }
        W1(99984, 0, u3Ar,u3Ai,u3Br,u3Bi, u1Ar,u1Ai,u1Br,u1Bi);
    }
}

// ---- fallback: single-wave, no workspace (R10-class) --------------------
__global__ __launch_bounds__(64, 1)
void ddlms_scan_fb(const float* __restrict__ xre,
                   const float* __restrict__ xim,
                   float* __restrict__ out) {
    const int l = (int)threadIdx.x;
    const int m = l & 31;
    const int half = l >> 5;
    constexpr float EPSv = 1e-8f;
    constexpr float LRW  = 1.0f / 64.0f;
    constexpr float LRF  = 1.0f / 128.0f;
    constexpr float LRB  = 1.0f / 2048.0f;
    const float B1 = 0.6324555320336759f;
    const float A1 = 0.31622776601683794f;
    const float A3 = 0.9486832980505138f;
    float wAr=0.f, wAi=0.f, wBr=0.f, wBi=0.f;
    float fr=1.f, fi=0.f, br=0.f, bi=0.f, psr=1.f, psj=0.f;
    float vr=0.f, vi=0.f, ewPr=0.f, ewPi=0.f, sP=0.f;
    float2* __restrict__ o2 = reinterpret_cast<float2*>(out);
    auto LOADU = [&](int nn, float& a, float& b_, float& c, float& d_) {
        const float* pr = xre + 4 * nn;
        const float* pi = xim + 4 * nn;
        a = pr[m]; c = pr[m + 32]; b_ = pi[m]; d_ = pi[m + 32];
    };
    float pAr,pAi,pBr,pBi, qAr,qAi,qBr,qBi, rAr,rAi,rBr,rBi;
    pAr=pAi=pBr=pBi=0.f;
    LOADU(0, qAr,qAi,qBr,qBi);
    LOADU(1, rAr,rAi,rBr,rBi);
    auto STEP = [&](int n,
        float& uPAr, float& uPAi, float& uPBr, float& uPBi,
        float& uCAr, float& uCAi, float& uCBr, float& uCBi,
        float& uNAr, float& uNAi, float& uNBr, float& uNBi) {
        {
            float gr = ewPr * uPAr; gr = fmaf( ewPi, uPAi, gr);
            float gi = ewPi * uPAr; gi = fmaf(-ewPr, uPAi, gi);
            wAr = fmaf(sP, gr, wAr); wAi = fmaf(sP, gi, wAi);
            float hr = ewPr * uPBr; hr = fmaf( ewPi, uPBi, hr);
            float hi = ewPi * uPBr; hi = fmaf(-ewPr, uPBi, hi);
            wBr = fmaf(sP, hr, wBr); wBi = fmaf(sP, hi, wBi);
        }
        float basr, basi;
        {
            float prr = wAr * uNAr; prr = fmaf(-wAi, uNAi, prr);
            prr = fmaf(wBr, uNBr, prr); prr = fmaf(-wBi, uNBi, prr);
            float pri = wAr * uNAi; pri = fmaf( wAi, uNAr, pri);
            pri = fmaf(wBr, uNBi, pri); pri = fmaf( wBi, uNBr, pri);
            basr = red32(prr); basi = red32(pri);
        }
        float uu = uCAr*uCAr; uu = fmaf(uCAi,uCAi,uu);
        uu = fmaf(uCBr,uCBr,uu); uu = fmaf(uCBi,uCBi,uu);
        float sN = LRW * __builtin_amdgcn_rcpf(red32(uu) + EPSv);
        float ccr = uCAr*uNAr; ccr = fmaf(uCAi,uNAi,ccr);
        ccr = fmaf(uCBr,uNBr,ccr); ccr = fmaf(uCBi,uNBi,ccr);
        float cci = uCAr*uNAi; cci = fmaf(-uCAi,uNAr,cci);
        cci = fmaf(uCBr,uNBi,cci); cci = fmaf(-uCBi,uNBr,cci);
        float sCr = sN * red32(ccr), sCi = sN * red32(cci);
        float kr = fmaf(vr, fr, -(vi * fi));
        float ki = fmaf(vr, fi,   vi * fr);
        float zr = kr + br, zi = ki + bi;
        if (m == 0) o2[2 * n + half] = make_float2(zr, zi);
        float magr = (fabsf(zr) > B1) ? A3 : A1;
        float dr   = (zr <= 0.f) ? -magr : magr;
        float magi = (fabsf(zi) > B1) ? A3 : A1;
        float di   = (zi <= 0.f) ? -magi : magi;
        float er = dr - zr, ei = di - zi;
        float v2  = fmaf(vr, vr, fmaf(vi, vi, EPSv));
        float rv  = __builtin_amdgcn_rcpf(v2);
        float gfr = fmaf(er, vr,   ei * vi)  * rv;
        float gfi = fmaf(ei, vr, -(er * vi)) * rv;
        float m2  = fmaf(gfr, gfr, gfi * gfi);
        float scf = fminf(1.f, 30.f * __builtin_amdgcn_rsqf(m2));
        float tf  = LRF * scf;
        float dbr = dr - br, dbi = di - bi;
        float ewr = fmaf(dbr, psr, -(dbi * psj)) - vr;
        float ewi = fmaf(dbr, psj,   dbi * psr)  - vi;
        float Dr = fmaf(ewr, sCr, -(ewi * sCi));
        float Di = fmaf(ewr, sCi,   ewi * sCr);
        vr = basr + Dr; vi = basi + Di;
        fr = fmaf(tf, gfr, fr); fi = fmaf(tf, gfi, fi);
        br = fmaf(LRB, er, br); bi = fmaf(LRB, ei, bi);
        float ff = fmaf(fr, fr, fi * fi);
        float rs = __builtin_amdgcn_rsqf(ff);
        psr = fr * rs; psj = -(fi * rs);
        ewPr = ewr; ewPi = ewi; sP = sN;
        int nn = n + 2; if (nn > NSTEPS - 1) nn = NSTEPS - 1;
        LOADU(nn, uPAr, uPAi, uPBr, uPBi);
    };
    int n = 0;
    for (int it = 0; it < 33328; ++it) {
        STEP(n,     pAr,pAi,pBr,pBi,  qAr,qAi,qBr,qBi,  rAr,rAi,rBr,rBi);
        STEP(n + 1, qAr,qAi,qBr,qBi,  rAr,rAi,rBr,rBi,  pAr,pAi,pBr,pBi);
        STEP(n + 2, rAr,rAi,rBr,rBi,  pAr,pAi,pBr,pBi,  qAr,qAi,qBr,qBi);
        n += 3;
    }
    STEP(99984, pAr,pAi,pBr,pBi, qAr,qAi,qBr,qBi, rAr,rAi,rBr,rBi);
}

extern "C" void kernel_launch(void* const* d_in, const int* in_sizes, int n_in,
                              void* d_out, int out_size, void* d_ws, size_t ws_size,
                              hipStream_t stream) {
    const float* xre = (const float*)d_in[0];
    const float* xim = (const float*)d_in[1];
    float* out = (float*)d_out;

    if (ws_size >= (size_t)NSTEPS * sizeof(float4)) {
        float4* tab = (float4*)d_ws;
        pre_tab<<<(NSTEPS + 255) / 256, 256, 0, stream>>>(xre, xim, tab, NSTEPS);
        ddlms_scan2<<<1, 128, 0, stream>>>(xre, xim, tab, out);
    } else {
        ddlms_scan_fb<<<1, 64, 0, stream>>>(xre, xim, out);
    }
}